// Round 1
// baseline (1178.969 us; speedup 1.0000x reference)
//
#include <hip/hip_runtime.h>
#include <stdint.h>

// Problem constants
#define BATCH 128
#define LFULL 4096
#define TT 48            // number of tags
#define NPOT 4094        // pot timesteps (L-2)
#define NBP  4093        // number of bp entries / stored state vectors
#define SEG  64          // backtrack segment length
#define NSEG 64          // ceil(NBP/SEG)
#define SLOT 192         // bytes per state slot (48 floats)

// ---------------------------------------------------------------------------
// Exact max over 48 floats (order-independent for exact value). max3-friendly.
__device__ __forceinline__ float maxtree48(const float* s) {
    float r[16];
#pragma unroll
    for (int j = 0; j < 16; ++j)
        r[j] = fmaxf(fmaxf(s[3*j], s[3*j+1]), s[3*j+2]);
#pragma unroll
    for (int j = 0; j < 8; ++j) r[j] = fmaxf(r[j], r[j+8]);
#pragma unroll
    for (int j = 0; j < 4; ++j) r[j] = fmaxf(r[j], r[j+4]);
    return fmaxf(fmaxf(r[0], r[1]), fmaxf(r[2], r[3]));
}

// ---------------------------------------------------------------------------
// K1: forward Viterbi scan (values only, no argmax). One wave per batch.
// Lane k holds transition column k in registers; full state vector replicated
// in every lane's registers, redistributed per step via LDS ping-pong.
// Stores state vectors s_0..s_4092 into the pot region of d_out (scratch).
// Also writes last_tag (byte) into bound[b][NSEG].
__global__ __launch_bounds__(64) void k_forward(const float* __restrict__ in,
                                                const float* __restrict__ trans,
                                                char* __restrict__ statesBase,
                                                unsigned char* __restrict__ bound) {
    const int b = blockIdx.x;
    const int lane = threadIdx.x;
    const int kk = (lane < TT) ? lane : 0;

    __shared__ float ldsT[TT * TT];
    __shared__ __align__(16) float lsbuf[2][TT];

    for (int i = lane; i < TT * TT; i += 64) ldsT[i] = trans[i];
    __syncthreads();

    float tcol[TT];
#pragma unroll
    for (int j = 0; j < TT; ++j) tcol[j] = ldsT[j * TT + kk];

    const float* inb = in + (size_t)b * (LFULL * TT);
    char* sb = statesBase + (size_t)b * NBP * SLOT;

    // s0 = pot[b,0,:] = in[b,1,:], replicated into every lane
    float sv[TT];
#pragma unroll
    for (int j = 0; j < TT; j += 4) {
        float4 v = *(const float4*)(inb + TT + j);
        sv[j] = v.x; sv[j+1] = v.y; sv[j+2] = v.z; sv[j+3] = v.w;
    }
    // store s_0 (slot 0) — re-load by lane to avoid runtime reg indexing
    if (lane < TT) ((float*)sb)[lane] = inb[TT + lane];

    // one Viterbi step: snew[k] = max_j(sv[j]+T[j][k]) + emit
    auto STEP = [&](int t, float e) {
        float s[TT];
#pragma unroll
        for (int j = 0; j < TT; ++j) s[j] = sv[j] + tcol[j];
        float m = maxtree48(s);
        float snew = m + e;
        int pp = t & 1;
        if (lane < TT) lsbuf[pp][lane] = snew;
        __syncthreads();
#pragma unroll
        for (int j = 0; j < TT; j += 4) {
            float4 v = *(const float4*)(&lsbuf[pp][j]);
            sv[j] = v.x; sv[j+1] = v.y; sv[j+2] = v.z; sv[j+3] = v.w;
        }
        if (t <= NBP - 1 && lane < TT)          // store s_t for t <= 4092
            *(float*)(sb + (size_t)t * SLOT + (size_t)lane * 4) = snew;
    };

    // emission for step t is pot[b,t,:] = in[b,t+1,:]
    auto LD = [&](int t) -> float {
        return (t <= NBP) ? inb[(size_t)(t + 1) * TT + kk] : 0.0f;
    };

    float e0 = LD(1), e1 = LD(2), e2 = LD(3), e3 = LD(4);
    int t = 1;
    for (; t + 3 <= NBP; t += 4) {
        STEP(t,     e0); e0 = LD(t + 4);
        STEP(t + 1, e1); e1 = LD(t + 5);
        STEP(t + 2, e2); e2 = LD(t + 6);
        STEP(t + 3, e3); e3 = LD(t + 7);
    }
    for (; t <= NBP; ++t) { STEP(t, e0); e0 = e1; e1 = e2; e2 = e3; }

    // last_tag = first-index argmax of final state
    if (lane == 0) {
        float best = sv[0]; int bi = 0;
#pragma unroll
        for (int j = 1; j < TT; ++j) {
            if (sv[j] > best) { best = sv[j]; bi = j; }
        }
        bound[b * (NSEG + 1) + NSEG] = (unsigned char)bi;
    }
}

// ---------------------------------------------------------------------------
// K2: recompute backpointers bp_i[k] = argmax_j(s_i[j] + T[j][k]) for ALL
// (b,i,k), massively parallel. One wave per (b, chunk of 16 i's). bp bytes
// overwrite the first 48 bytes of each state slot (slot owned by this wave,
// fully read before written).
#define CHUNK 16
__global__ __launch_bounds__(256) void k_bp(const float* __restrict__ trans,
                                            char* __restrict__ statesBase) {
    const int lane = threadIdx.x & 63;
    const int wv = threadIdx.x >> 6;
    const int b = blockIdx.y * 4 + wv;
    const int i0 = blockIdx.x * CHUNK;
    const int kk = (lane < TT) ? lane : 0;

    __shared__ float ldsT[TT * TT];
    for (int i = threadIdx.x; i < TT * TT; i += 256) ldsT[i] = trans[i];
    __syncthreads();

    float tcol[TT];
#pragma unroll
    for (int j = 0; j < TT; ++j) tcol[j] = ldsT[j * TT + kk];

    char* sb = statesBase + (size_t)b * NBP * SLOT;

    for (int ii = 0; ii < CHUNK; ++ii) {
        int i = i0 + ii;
        if (i >= NBP) break;                     // uniform across wave
        const float* sp = (const float*)(sb + (size_t)i * SLOT);
        float sv[TT];
#pragma unroll
        for (int j = 0; j < TT; j += 4) {
            float4 v = *(const float4*)(sp + j);
            sv[j] = v.x; sv[j+1] = v.y; sv[j+2] = v.z; sv[j+3] = v.w;
        }
        float best = sv[0] + tcol[0]; int bi = 0;
#pragma unroll
        for (int j = 1; j < TT; ++j) {
            float v = sv[j] + tcol[j];
            if (v > best) { best = v; bi = j; }  // strict > : first-index wins
        }
        if (lane < TT)
            *(unsigned char*)(sb + (size_t)i * SLOT + lane) = (unsigned char)bi;
    }
}

// ---------------------------------------------------------------------------
// K3: compose each 64-step segment of backpointer maps into one map G_s
// (tag at segment end -> tag at segment start). Lane x traces start value x.
__global__ __launch_bounds__(64) void k_compose(const char* __restrict__ statesBase,
                                                unsigned char* __restrict__ G) {
    const int s = blockIdx.x, b = blockIdx.y;
    const int i0 = s * SEG;
    const int cnt = (SEG < NBP - i0) ? SEG : (NBP - i0);
    const int lane = threadIdx.x;

    __shared__ unsigned char lbp[SEG * TT];
    const char* sb = statesBase + (size_t)b * NBP * SLOT;
    for (int ii = 0; ii < cnt; ++ii) {
        if (lane < 12)
            ((uint32_t*)lbp)[ii * 12 + lane] =
                *(const uint32_t*)(sb + (size_t)(i0 + ii) * SLOT + (size_t)lane * 4);
    }
    __syncthreads();

    if (lane < TT) {
        int M = lane;
        for (int ii = cnt - 1; ii >= 0; --ii) M = lbp[ii * TT + M];
        G[(b * NSEG + s) * TT + lane] = (unsigned char)M;
    }
}

// ---------------------------------------------------------------------------
// K4: chain across segments: boundary tag at each segment start.
__global__ void k_boundary(const unsigned char* __restrict__ G,
                           unsigned char* __restrict__ bound) {
    int b = threadIdx.x;                 // 128 threads, 1 block
    int x = bound[b * (NSEG + 1) + NSEG];
    for (int s = NSEG - 1; s >= 0; --s) {
        x = G[(b * NSEG + s) * TT + x];
        bound[b * (NSEG + 1) + s] = x;
    }
}

// ---------------------------------------------------------------------------
// K5: fill tags within each segment by re-walking its bp maps from the known
// entering boundary tag. Writes final float tags.
__global__ __launch_bounds__(64) void k_fill(const char* __restrict__ statesBase,
                                             const unsigned char* __restrict__ bound,
                                             float* __restrict__ tags) {
    const int s = blockIdx.x, b = blockIdx.y;
    const int i0 = s * SEG;
    const int cnt = (SEG < NBP - i0) ? SEG : (NBP - i0);
    const int lane = threadIdx.x;

    __shared__ unsigned char lbp[SEG * TT];
    const char* sb = statesBase + (size_t)b * NBP * SLOT;
    for (int ii = 0; ii < cnt; ++ii) {
        if (lane < 12)
            ((uint32_t*)lbp)[ii * 12 + lane] =
                *(const uint32_t*)(sb + (size_t)(i0 + ii) * SLOT + (size_t)lane * 4);
    }
    __syncthreads();

    if (lane == 0) {
        int x = bound[b * (NSEG + 1) + s + 1];   // tag at position (s+1)*SEG (or last_tag)
        if (s == NSEG - 1)
            tags[(size_t)b * NPOT + (NPOT - 1)] = (float)x;
        for (int ii = cnt - 1; ii >= 0; --ii) {
            x = lbp[ii * TT + x];
            tags[(size_t)b * NPOT + i0 + ii] = (float)x;
        }
    }
}

// ---------------------------------------------------------------------------
// K6: final copies — pot = in[:,1:-1,:] and transitions passthrough.
__global__ __launch_bounds__(256) void k_copy(const float* __restrict__ in,
                                              const float* __restrict__ trans,
                                              float* __restrict__ out) {
    const int potN4 = (BATCH * NPOT * TT) / 4;   // 6,288,384 float4s
    const int rowN = NPOT * TT;                  // 196,512
    int idx = blockIdx.x * 256 + threadIdx.x;
    if (idx < potN4) {
        int p4 = idx * 4;
        int b = p4 / rowN;
        int off = p4 - b * rowN;
        float4 v = *(const float4*)(in + (size_t)b * (LFULL * TT) + off + TT);
        *(float4*)(out + p4) = v;
    } else if (idx < potN4 + (TT * TT) / 4) {
        int q = idx - potN4;
        *(float4*)(out + (size_t)BATCH * NPOT * TT + (size_t)q * 4) =
            *(const float4*)(trans + (size_t)q * 4);
    }
}

// ---------------------------------------------------------------------------
extern "C" void kernel_launch(void* const* d_in, const int* in_sizes, int n_in,
                              void* d_out, int out_size, void* d_ws, size_t ws_size,
                              hipStream_t stream) {
    (void)in_sizes; (void)n_in; (void)d_ws; (void)ws_size; (void)out_size;

    const float* in = (const float*)d_in[0];
    const float* trans = (const float*)d_in[1];
    float* out = (float*)d_out;

    // Scratch carved out of d_out (stream-ordered so everything is rewritten):
    //  - pot region   [0 .. 100.6MB): state vectors, then bp bytes in-place
    //  - trans region [2304 floats]: boundary tags (128 x 65 bytes)
    //  - tags region  [524032 floats]: segment maps G, then final tags
    char* statesBase = (char*)d_out;
    unsigned char* bound = (unsigned char*)(out + (size_t)BATCH * NPOT * TT);
    unsigned char* G = (unsigned char*)(out + (size_t)BATCH * NPOT * TT + TT * TT);
    float* tags = out + (size_t)BATCH * NPOT * TT + TT * TT;

    k_forward <<<dim3(BATCH),        dim3(64),  0, stream>>>(in, trans, statesBase, bound);
    k_bp      <<<dim3(256, 32),      dim3(256), 0, stream>>>(trans, statesBase);
    k_compose <<<dim3(NSEG, BATCH),  dim3(64),  0, stream>>>(statesBase, G);
    k_boundary<<<dim3(1),            dim3(BATCH), 0, stream>>>(G, bound);
    k_fill    <<<dim3(NSEG, BATCH),  dim3(64),  0, stream>>>(statesBase, bound, tags);

    int total4 = (BATCH * NPOT * TT) / 4 + (TT * TT) / 4;
    k_copy    <<<dim3((total4 + 255) / 256), dim3(256), 0, stream>>>(in, trans, out);
}